// Round 5
// baseline (399.560 us; speedup 1.0000x reference)
//
#include <hip/hip_runtime.h>

// Problem constants
#define B_    32
#define S_    4096
#define CIN   21
#define DM    512
#define KW    8          // window taps
#define NK    74
#define PROJIN 1534      // 73*21 + 1

// MFMA-layout constants
#define CP    24         // channels padded to 24 (pad weights = 0)
#define KSEG  192        // KW*CP — one K-segment
#define WSTR  200        // W LDS row stride in shorts (192 + 8 pad, 400B = 4 mod 32 dwords)
#define DT    128        // d-tile per block
#define WT    128        // w-tile per block
#define SROWS 136        // x slab rows = WT + 8

typedef __attribute__((ext_vector_type(8))) short bf16x8;
typedef __attribute__((ext_vector_type(4))) float f32x4;

__device__ __forceinline__ unsigned short f2bf_rne(float x) {
  unsigned u = __float_as_uint(x);
  unsigned r = (u + 0x7FFFu + ((u >> 16) & 1u)) >> 16;
  return (unsigned short)r;
}
__device__ __forceinline__ float bf2f(unsigned short b) {
  return __uint_as_float(((unsigned)b) << 16);
}

// ---------------------------------------------------------------------------
// Prep: W_eff[d][k*24+c] = sum_{n<73} proj_w[d,n*21+c]*kernels[n,k]
//                          + (c==0)*proj_w[d,1533]*kernels[73,k];  c>=21 -> 0
// Split into bf16 hi/lo, store row-major [512][192] each.
// ---------------------------------------------------------------------------
__global__ __launch_bounds__(256) void build_weff(
    const float* __restrict__ kernels, const float* __restrict__ proj_w,
    unsigned short* __restrict__ wh, unsigned short* __restrict__ wl) {
  __shared__ float pw[PROJIN];
  __shared__ float kk[NK * KW];
  const int d = blockIdx.x, tid = threadIdx.x;
  for (int i = tid; i < PROJIN; i += 256) pw[i] = proj_w[d * PROJIN + i];
  for (int i = tid; i < NK * KW; i += 256) kk[i] = kernels[i];
  __syncthreads();
  if (tid < KSEG) {
    const int k = tid / CP, c = tid % CP;
    float acc = 0.f;
    if (c < CIN) {
      #pragma unroll 1
      for (int n = 0; n < 73; ++n)
        acc = fmaf(pw[n * CIN + c], kk[n * KW + k], acc);
      if (c == 0) acc = fmaf(pw[PROJIN - 1], kk[73 * KW + k], acc);
    }
    const unsigned short h = f2bf_rne(acc);
    wh[d * KSEG + tid] = h;
    wl[d * KSEG + tid] = f2bf_rne(acc - bf2f(h));
  }
}

// ---------------------------------------------------------------------------
// out[b,d,w] = proj_b[d] + sum_kc Weff * x-window, via bf16-split MFMA:
//   phase A: Whi*(Xhi + Xlo), phase B (after W restage): Wlo*Xhi.
// Block: 256 thr = 4 waves (2w x 2d of 64x64). Wave tile: 4x4 frags 16x16.
// X is the MFMA A-operand -> D rows (reg idx) = w -> float4 C-stores.
// ---------------------------------------------------------------------------
__global__ __launch_bounds__(256, 2) void conv_mfma(
    const float* __restrict__ x, const unsigned short* __restrict__ wh,
    const unsigned short* __restrict__ wl, const float* __restrict__ proj_b,
    float* __restrict__ out) {
  __shared__ __align__(16) unsigned short Wt[DT * WSTR];   // 51,200 B
  __shared__ __align__(16) unsigned short Xh[SROWS * CP];  //  6,528 B
  __shared__ __align__(16) unsigned short Xl[SROWS * CP];  //  6,528 B
  __shared__ float bl[DT];                                 //    512 B

  const int tid = threadIdx.x;
  const int blk = blockIdx.x;
  const int dt = blk & 3;
  const int wt = (blk >> 2) & 31;
  const int b  = blk >> 7;
  const int d0 = dt * DT;
  const int w0 = wt * WT;

  // ---- stage x slab: row s <-> global w = w0-7+s, fp32 -> bf16 hi/lo ----
  const float* xb = x + (size_t)b * (S_ * CIN);
  for (int i = tid; i < SROWS * CP; i += 256) {
    const int s = i / CP, cc = i - s * CP;
    const int wg = w0 - 7 + s;
    float v = 0.f;
    if (cc < CIN && wg >= 0 && wg < S_) v = xb[wg * CIN + cc];
    const unsigned short h = f2bf_rne(v);
    Xh[i] = h;
    Xl[i] = f2bf_rne(v - bf2f(h));
  }
  // ---- stage Whi chunk: [DT][192] global -> [DT][WSTR] LDS, b128 units ----
  for (int i = tid; i < DT * (KSEG / 8); i += 256) {
    const int r = i / (KSEG / 8), j = i - r * (KSEG / 8);
    *(bf16x8*)&Wt[r * WSTR + j * 8] =
        *(const bf16x8*)&wh[(size_t)(d0 + r) * KSEG + j * 8];
  }
  if (tid < DT) bl[tid] = proj_b[d0 + tid];
  __syncthreads();

  const int l     = tid & 63;
  const int wave  = tid >> 6;
  const int l15   = l & 15;
  const int q     = l >> 4;               // lane quarter 0..3
  const int q8    = q * 8;
  const int wavew = (wave & 1) * 64;
  const int waved = (wave >> 1) * 64;

  // per-step X offset (in shorts): kappa = 32s + q8 -> (k = /24, c0 = %24)
  int koffS[6];
  #pragma unroll
  for (int s = 0; s < 6; ++s) {
    const int k0 = 32 * s + q8;
    const int k = k0 / CP, c0 = k0 - k * CP;
    koffS[s] = k * CP + c0;               // slab idx addend: row +k, col c0
  }
  int xbaseS[4], wbaseS[4];
  #pragma unroll
  for (int m = 0; m < 4; ++m) xbaseS[m] = (wavew + m * 16 + l15) * CP;
  #pragma unroll
  for (int n = 0; n < 4; ++n) wbaseS[n] = (waved + n * 16 + l15) * WSTR + q8;

  f32x4 acc[4][4] = {};

  // ---- phase A: Whi * Xhi + Whi * Xlo ----
  #pragma unroll
  for (int s = 0; s < 6; ++s) {
    bf16x8 fw[4], fh[4], fl[4];
    #pragma unroll
    for (int n = 0; n < 4; ++n)
      fw[n] = *(const bf16x8*)&Wt[wbaseS[n] + s * 32];
    #pragma unroll
    for (int m = 0; m < 4; ++m) {
      fh[m] = *(const bf16x8*)&Xh[xbaseS[m] + koffS[s]];
      fl[m] = *(const bf16x8*)&Xl[xbaseS[m] + koffS[s]];
    }
    #pragma unroll
    for (int m = 0; m < 4; ++m)
      #pragma unroll
      for (int n = 0; n < 4; ++n) {
        acc[m][n] = __builtin_amdgcn_mfma_f32_16x16x32_bf16(
            fh[m], fw[n], acc[m][n], 0, 0, 0);
        acc[m][n] = __builtin_amdgcn_mfma_f32_16x16x32_bf16(
            fl[m], fw[n], acc[m][n], 0, 0, 0);
      }
  }
  __syncthreads();
  // ---- restage W chunk with Wlo ----
  for (int i = tid; i < DT * (KSEG / 8); i += 256) {
    const int r = i / (KSEG / 8), j = i - r * (KSEG / 8);
    *(bf16x8*)&Wt[r * WSTR + j * 8] =
        *(const bf16x8*)&wl[(size_t)(d0 + r) * KSEG + j * 8];
  }
  __syncthreads();
  // ---- phase B: Wlo * Xhi ----
  #pragma unroll
  for (int s = 0; s < 6; ++s) {
    bf16x8 fw[4], fh[4];
    #pragma unroll
    for (int n = 0; n < 4; ++n)
      fw[n] = *(const bf16x8*)&Wt[wbaseS[n] + s * 32];
    #pragma unroll
    for (int m = 0; m < 4; ++m)
      fh[m] = *(const bf16x8*)&Xh[xbaseS[m] + koffS[s]];
    #pragma unroll
    for (int m = 0; m < 4; ++m)
      #pragma unroll
      for (int n = 0; n < 4; ++n)
        acc[m][n] = __builtin_amdgcn_mfma_f32_16x16x32_bf16(
            fh[m], fw[n], acc[m][n], 0, 0, 0);
  }

  // ---- epilogue: bias + float4 stores (reg idx r = consecutive w) ----
  const size_t ob = (size_t)b * DM * S_;
  #pragma unroll
  for (int n = 0; n < 4; ++n) {
    const int d = d0 + waved + n * 16 + l15;
    const float bias = bl[waved + n * 16 + l15];
    #pragma unroll
    for (int m = 0; m < 4; ++m) {
      const int w = w0 + wavew + m * 16 + q * 4;
      f32x4 v = acc[m][n];
      v = v + bias;
      *(f32x4*)&out[ob + (size_t)d * S_ + w] = v;
    }
  }
}

// ---------------------------------------------------------------------------
extern "C" void kernel_launch(void* const* d_in, const int* in_sizes, int n_in,
                              void* d_out, int out_size, void* d_ws, size_t ws_size,
                              hipStream_t stream) {
  const float* x       = (const float*)d_in[0];
  const float* kernels = (const float*)d_in[1];
  const float* proj_w  = (const float*)d_in[2];
  const float* proj_b  = (const float*)d_in[3];
  float* out = (float*)d_out;

  unsigned short* weff_hi = (unsigned short*)d_ws;              // 512*192 u16
  unsigned short* weff_lo = weff_hi + (size_t)DM * KSEG;        // +196,608 B

  build_weff<<<DM, 256, 0, stream>>>(kernels, proj_w, weff_hi, weff_lo);
  conv_mfma<<<B_ * 32 * 4, 256, 0, stream>>>(x, weff_hi, weff_lo, proj_b, out);
}